// Round 11
// baseline (2786.194 us; speedup 1.0000x reference)
//
#include <hip/hip_runtime.h>

typedef __attribute__((ext_vector_type(8))) short short8;   // 8 bf16 in 4 VGPRs
typedef __attribute__((ext_vector_type(4))) float f32x4;
typedef __attribute__((ext_vector_type(4))) unsigned int u32x4;
typedef __attribute__((ext_vector_type(2))) unsigned int u32x2;
typedef unsigned short u16;
typedef unsigned int u32;

static constexpr int TT = 512;
static constexpr int HDim = 1024;
static constexpr int NBH = 64 * 1024;          // B*HD = 65536
static constexpr int NBLK = 64;                // 4 bg (16 rows) x 16 hg (64 h)
static constexpr int VBUF = 65536;             // u32 per half: 64 rows x 512 pairs x {pay,tag}

__device__ __forceinline__ u16 f2bf(float f) {             // RNE f32->bf16
  u32 u = __float_as_uint(f);
  u32 r = u + 0x7FFFu + ((u >> 16) & 1u);
  return (u16)(r >> 16);
}
__device__ __forceinline__ float bf2f(u16 u) {
  return __uint_as_float(((u32)u) << 16);
}
__device__ __forceinline__ float sigmoidf_(float v) {
  return 1.0f / (1.0f + __expf(-v));
}

#define WAITVM(n) asm volatile("s_waitcnt vmcnt(" #n ")" ::: "memory")
#define SBAR() __builtin_amdgcn_sched_barrier(0)
// non-rematerializable weight load (plain cache path; long-lived regs)
#define WLD(dst, p) asm volatile("global_load_dwordx4 %0, %1, off" : "=v"(dst) : "v"(p))
// agent-coherent (sc1) ops: L3 is the coherence point across XCDs
#define PLD(dst, p) asm volatile("global_load_dwordx4 %0, %1, off sc1" : "=v"(dst) : "v"(p) : "memory")
#define PLDD(dst, p) asm volatile("global_load_dword %0, %1, off sc1" : "=v"(dst) : "v"(p) : "memory")
#define PST2(p, v2) asm volatile("global_store_dwordx2 %0, %1, off sc1" :: "v"(p), "v"(v2) : "memory")
#define MFMA(a, b, c) __builtin_amdgcn_mfma_f32_16x16x32_bf16(a, b, c, 0, 0, 0)

// ------- prep: Wih->bf16; V0 slots {pay,tag=0} in buf0; buf1 tags=~0 -------
__global__ void prep_kernel(const float* __restrict__ x, const float* __restrict__ Q0,
                            const float* __restrict__ Wih, const float* __restrict__ uVr,
                            const float* __restrict__ uV2,
                            u16* __restrict__ Wih_bf, u32* __restrict__ Vpt) {
  const int NW = 2048 * 1024;
  int stride = gridDim.x * blockDim.x;
  int gid = blockIdx.x * blockDim.x + threadIdx.x;
  for (int i = gid; i < NW; i += stride) Wih_bf[i] = f2bf(Wih[i]);
  for (int p = gid; p < 32768; p += stride) {          // 64 rows x 512 k-pairs
    int s = p * 2;                                     // u32 slot base = row*1024 + 2*kp
    int h0 = s & 1023;
    float g0 = sigmoidf_(uV2[h0]) * tanhf(uVr[h0]);
    float g1 = sigmoidf_(uV2[h0 + 1]) * tanhf(uVr[h0 + 1]);
    u32 pay = (u32)f2bf(x[s] + g0 * Q0[s]) |
              ((u32)f2bf(x[s + 1] + g1 * Q0[s + 1]) << 16);
    Vpt[s] = pay;            Vpt[s + 1] = 0u;          // V_0, tag 0
    Vpt[VBUF + s] = 0u;      Vpt[VBUF + s + 1] = 0xFFFFFFFFu;  // buf1 invalid
  }
}

// ---------------- A_all = x @ WA^T  (M=32768,N=1024,K=1024), bf16 out ------
__global__ __launch_bounds__(256) void agemm_kernel(const float* __restrict__ X,
                                                    const float* __restrict__ W,
                                                    u16* __restrict__ C) {
  __shared__ u16 As[128 * 64];
  __shared__ u16 Bs[128 * 64];
  int tid = threadIdx.x;
  int l = tid & 63, w = tid >> 6;
  int n = l & 15, rowg = l >> 4;
  int wr = w >> 1, wc = w & 1;
  int bm = blockIdx.x >> 3, bn = blockIdx.x & 7;
  long m0 = (long)bm * 128;
  int n0 = bn * 128;
  int srow = tid >> 4;
  int sk4 = (tid & 15) * 4;

  f32x4 acc[4][4];
#pragma unroll
  for (int r = 0; r < 4; ++r)
#pragma unroll
    for (int c = 0; c < 4; ++c) acc[r][c] = (f32x4){0.f, 0.f, 0.f, 0.f};

  for (int kt = 0; kt < 16; ++kt) {
    __syncthreads();
#pragma unroll
    for (int i = 0; i < 8; ++i) {
      int row = srow + i * 16;
      float4 va = *(const float4*)(X + (m0 + row) * 1024 + kt * 64 + sk4);
      u32 lo = (u32)f2bf(va.x) | ((u32)f2bf(va.y) << 16);
      u32 hi = (u32)f2bf(va.z) | ((u32)f2bf(va.w) << 16);
      *(uint2*)(As + row * 64 + sk4) = make_uint2(lo, hi);
      float4 vb = *(const float4*)(W + (long)(n0 + row) * 1024 + kt * 64 + sk4);
      u32 lo2 = (u32)f2bf(vb.x) | ((u32)f2bf(vb.y) << 16);
      u32 hi2 = (u32)f2bf(vb.z) | ((u32)f2bf(vb.w) << 16);
      *(uint2*)(Bs + row * 64 + sk4) = make_uint2(lo2, hi2);
    }
    __syncthreads();
#pragma unroll
    for (int ks = 0; ks < 2; ++ks) {
      short8 af[4], bfr[4];
#pragma unroll
      for (int r = 0; r < 4; ++r)
        af[r] = *(const short8*)(As + (wr * 64 + r * 16 + n) * 64 + ks * 32 + rowg * 8);
#pragma unroll
      for (int c = 0; c < 4; ++c)
        bfr[c] = *(const short8*)(Bs + (wc * 64 + c * 16 + n) * 64 + ks * 32 + rowg * 8);
#pragma unroll
      for (int r = 0; r < 4; ++r)
#pragma unroll
        for (int c = 0; c < 4; ++c)
          acc[r][c] = __builtin_amdgcn_mfma_f32_16x16x32_bf16(af[r], bfr[c], acc[r][c], 0, 0, 0);
    }
  }
#pragma unroll
  for (int r = 0; r < 4; ++r)
#pragma unroll
    for (int c = 0; c < 4; ++c)
#pragma unroll
      for (int q = 0; q < 4; ++q) {
        long row = m0 + wr * 64 + r * 16 + rowg * 4 + q;
        int col = n0 + wc * 64 + c * 16 + n;
        C[row * 1024 + col] = f2bf(acc[r][c][q]);
      }
}

// ---------------- persistent scan (r7 base + per-producer-wave canary) -----
// 64 blocks = 4 bg (16 rows) x 16 hg (64 h), 512 thr = 8 waves, K-split 128/wave.
// V slots {pay(2bf16), tag=t} via one dwordx2 sc1: no drain, no flags.
// Consumer wave gates on 16 canaries = the LAST-issued store (row15, r=3)
// of each of its 16 producer waves, then does ONE tagged sweep (rare retry).
__global__ __launch_bounds__(512, 2)
void scan_kernel(const u16* __restrict__ Wih_bf, const u16* __restrict__ A_bf,
                 const float* __restrict__ x, const float* __restrict__ S0,
                 const float* __restrict__ PFB, const float* __restrict__ HWb,
                 const float* __restrict__ uVr, const float* __restrict__ uV2,
                 u32* __restrict__ Vpt, float* __restrict__ out) {
  __shared__ f32x4 red[8][8][64];              // [j-tile][wave][lane]
  const int tid = threadIdx.x, bk = blockIdx.x;
  const int bg = bk >> 4, hg = bk & 15;
  const int l = tid & 63, w = tid >> 6;
  const int n = l & 15, rowg = l >> 4, hl = n & 7;
  const bool isF = (n < 8);
  const int h = hg * 64 + w * 8 + hl;          // wave w's output h (post-reduce)

  // weights: 8 j-tiles x 4 k-slices = 32 short8 = 128 regs, asm-pinned
  short8 bw[8][4];
  {
    const int fOff = isF ? 0 : HDim;
#pragma unroll
    for (int jt = 0; jt < 8; ++jt) {
      const u16* wp = Wih_bf + (long)(fOff + hg * 64 + jt * 8 + hl) * 1024 + w * 128 + rowg * 8;
      WLD(bw[jt][0], wp);      WLD(bw[jt][1], wp + 32);
      WLD(bw[jt][2], wp + 64); WLD(bw[jt][3], wp + 96);
    }
  }
  WAITVM(0); SBAR();

  const float pfb = PFB[h], hwb = HWb[h];
  const float gh = sigmoidf_(uV2[h]) * tanhf(uVr[h]);

  const int row0 = bg * 16 + rowg * 4;
  int rowoff[4];
  float S[4];
#pragma unroll
  for (int r = 0; r < 4; ++r) { rowoff[r] = (row0 + r) * 1024 + h; S[r] = S0[rowoff[r]]; }

  // sweep/A-frag base: row = bg*16 + n, k = w*128 + s*32 + rowg*8 (+e)
  const u32* pbase = Vpt + (bg * 16 + n) * 1024 + w * 128 + rowg * 8;
  // canary: tag of pair (P*32 + wq*4 + 3) in row bg*16+15 — the LAST store
  // (r=3 group) issued by producer block P = 2w|(l&1), wave wq = (l>>1)&7
  const u32* cbase = Vpt + (bg * 16 + 15) * 1024
                   + ((2 * w + (l & 1)) * 64 + ((l >> 1) & 7) * 8 + 6) + 1;

  float xq[4], xn[4], av[4], Qs[4];
#pragma unroll
  for (int r = 0; r < 4; ++r) {
    xq[r] = x[rowoff[r]];
    xn[r] = x[NBH + rowoff[r]];
    av[r] = bf2f(A_bf[rowoff[r]]);
  }

#pragma unroll 1
  for (int t = 0; t < TT; ++t) {
    const u32 tv = (u32)t;
    const int half = (t & 1);

    // ---- canary gate: 16 producer-wave last-stores, pipelined depth-2
    {
      const u32* cb = cbase + half * VBUF;
      u32 c0, c1;
      PLDD(c0, cb);
      PLDD(c1, cb);
      while (true) {
        WAITVM(1); SBAR();
        if (__all(c0 == tv)) break;
        c0 = c1;
        PLDD(c1, cb);
      }
    }

    // ---- ONE tagged data sweep (tags self-validate; retry now rare)
    const u32* pb = pbase + half * VBUF;
    u32x4 q0a, q0b, q1a, q1b, q2a, q2b, q3a, q3b;
    while (true) {
      PLD(q0a, pb);      PLD(q0b, pb + 4);
      PLD(q1a, pb + 32); PLD(q1b, pb + 36);
      PLD(q2a, pb + 64); PLD(q2b, pb + 68);
      PLD(q3a, pb + 96); PLD(q3b, pb + 100);
      WAITVM(0); SBAR();
      bool ok = (q0a[1] == tv) & (q0a[3] == tv) & (q0b[1] == tv) & (q0b[3] == tv)
              & (q1a[1] == tv) & (q1a[3] == tv) & (q1b[1] == tv) & (q1b[3] == tv)
              & (q2a[1] == tv) & (q2a[3] == tv) & (q2b[1] == tv) & (q2b[3] == tv)
              & (q3a[1] == tv) & (q3a[3] == tv) & (q3b[1] == tv) & (q3b[3] == tv);
      if (__all(ok)) break;
    }

    // ---- deferred Y stores from previous step (ack drains under compute)
    if (t > 0) {
      const long pvbase = (long)(t - 1) * NBH;
#pragma unroll
      for (int r = 0; r < 4; ++r)
        if (isF) out[pvbase + rowoff[r]] = Qs[r];
    }

    // ---- extract payloads -> A fragments; MFMA (data already in regs)
    u32x4 p0 = {q0a[0], q0a[2], q0b[0], q0b[2]};
    u32x4 p1 = {q1a[0], q1a[2], q1b[0], q1b[2]};
    u32x4 p2 = {q2a[0], q2a[2], q2b[0], q2b[2]};
    u32x4 p3 = {q3a[0], q3a[2], q3b[0], q3b[2]};
    short8 va0 = __builtin_bit_cast(short8, p0);
    short8 va1 = __builtin_bit_cast(short8, p1);
    short8 va2 = __builtin_bit_cast(short8, p2);
    short8 va3 = __builtin_bit_cast(short8, p3);

    f32x4 pa[8];
#pragma unroll
    for (int jt = 0; jt < 8; ++jt) pa[jt] = (f32x4){0.f, 0.f, 0.f, 0.f};
#pragma unroll
    for (int jt = 0; jt < 8; ++jt) pa[jt] = MFMA(va0, bw[jt][0], pa[jt]);
#pragma unroll
    for (int jt = 0; jt < 8; ++jt) pa[jt] = MFMA(va1, bw[jt][1], pa[jt]);
#pragma unroll
    for (int jt = 0; jt < 8; ++jt) pa[jt] = MFMA(va2, bw[jt][2], pa[jt]);
#pragma unroll
    for (int jt = 0; jt < 8; ++jt) pa[jt] = MFMA(va3, bw[jt][3], pa[jt]);

    // ---- cross-wave K-reduction
#pragma unroll
    for (int jt = 0; jt < 8; ++jt) red[jt][w][l] = pa[jt];
    __syncthreads();
    f32x4 fr = red[w][0][l] + red[w][1][l] + red[w][2][l] + red[w][3][l]
             + red[w][4][l] + red[w][5][l] + red[w][6][l] + red[w][7][l];
    __syncthreads();                            // protect red reuse next step

    // ---- gates, state update, tagged V stores (fire-and-forget)
    u32* vnext = Vpt + ((t + 1) & 1) * VBUF;
    const long tbase = (long)t * NBH;
#pragma unroll
    for (int r = 0; r < 4; ++r) {
      float mine = fr[r];
      float other = __shfl_xor(mine, 8, 64);
      float Fi = isF ? mine : other;
      float Ri = isF ? other : mine;
      float F = sigmoidf_(Fi + pfb);
      float Rg = sigmoidf_(Ri + hwb);
      S[r] = F * S[r] + (1.0f - F) * av[r];
      float Q = Rg * S[r] + (1.0f - Rg) * xq[r];
      Qs[r] = Q;
      if (t < TT - 1) {
        u32 word = (u32)f2bf(xn[r] + gh * Q);
        u32 othw = (u32)__shfl_xor((int)word, 1, 64);
        if (isF && (hl & 1) == 0) {
          u32x2 pv = {word | (othw << 16), (u32)(t + 1)};
          PST2(vnext + rowoff[r], pv);          // {pay, tag} in one 8B store
        }
      }
    }

    if (t == TT - 1) {
#pragma unroll
      for (int r = 0; r < 4; ++r)
        if (isF) {
          out[tbase + rowoff[r]] = Qs[r];
          out[(long)TT * NBH + rowoff[r]] = Qs[r];            // Qf
          out[(long)TT * NBH + NBH + rowoff[r]] = S[r];       // Sf
        }
      break;
    }

    // ---- prefetch next step's scalars (in flight across the next canary)
    const long nb = tbase + NBH;
    const int tn = (t + 2 < TT) ? (t + 2) : (TT - 1);
    const long nb2 = (long)tn * NBH;
#pragma unroll
    for (int r = 0; r < 4; ++r) {
      xq[r] = x[nb + rowoff[r]];
      av[r] = bf2f(A_bf[nb + rowoff[r]]);
      xn[r] = x[nb2 + rowoff[r]];
    }
  }
}

extern "C" void kernel_launch(void* const* d_in, const int* in_sizes, int n_in,
                              void* d_out, int out_size, void* d_ws, size_t ws_size,
                              hipStream_t stream) {
  const float* x   = (const float*)d_in[0];
  const float* Q0  = (const float*)d_in[1];
  const float* S0  = (const float*)d_in[2];
  const float* Wih = (const float*)d_in[3];
  const float* WA  = (const float*)d_in[4];
  const float* uVr = (const float*)d_in[5];
  const float* uV2 = (const float*)d_in[6];
  const float* PFB = (const float*)d_in[7];
  const float* HWb = (const float*)d_in[8];
  float* out = (float*)d_out;

  char* ws = (char*)d_ws;
  u16* A_bf   = (u16*)(ws);                 // 67,108,864 B : A_all bf16 [T*B][HD]
  u16* Wih_bf = (u16*)(ws + 67108864);      //  4,194,304 B
  u32* Vpt    = (u32*)(ws + 71303168);      //    524,288 B : ping-pong {pay,tag}
  (void)in_sizes; (void)n_in; (void)out_size; (void)ws_size;

  prep_kernel<<<2048, 256, 0, stream>>>(x, Q0, Wih, uVr, uV2, Wih_bf, Vpt);
  agemm_kernel<<<2048, 256, 0, stream>>>(x, WA, A_bf);
  scan_kernel<<<NBLK, 512, 0, stream>>>(Wih_bf, A_bf, x, S0, PFB, HWb, uVr, uV2, Vpt, out);
}

// Round 13
// 2443.287 us; speedup vs baseline: 1.1403x; 1.1403x over previous
//
#include <hip/hip_runtime.h>

typedef __attribute__((ext_vector_type(8))) short short8;   // 8 bf16 in 4 VGPRs
typedef __attribute__((ext_vector_type(4))) float f32x4;
typedef __attribute__((ext_vector_type(4))) unsigned int u32x4;
typedef __attribute__((ext_vector_type(2))) unsigned int u32x2;
typedef unsigned short u16;
typedef unsigned int u32;

static constexpr int TT = 512;
static constexpr int HDim = 1024;
static constexpr int NBH = 64 * 1024;          // B*HD = 65536
static constexpr int NBLK = 64;                // 4 bg (16 rows) x 16 hg (64 h)
static constexpr int VBUF = 65536;             // u32 per half: 64 rows x 512 pairs x {pay,tag}

__device__ __forceinline__ u16 f2bf(float f) {             // RNE f32->bf16
  u32 u = __float_as_uint(f);
  u32 r = u + 0x7FFFu + ((u >> 16) & 1u);
  return (u16)(r >> 16);
}
__device__ __forceinline__ float bf2f(u16 u) {
  return __uint_as_float(((u32)u) << 16);
}
__device__ __forceinline__ float sigmoidf_(float v) {
  return 1.0f / (1.0f + __expf(-v));
}

#define WAITVM(n) asm volatile("s_waitcnt vmcnt(" #n ")" ::: "memory")
#define SBAR() __builtin_amdgcn_sched_barrier(0)
// non-rematerializable weight load (plain cache path; long-lived regs)
#define WLD(dst, p) asm volatile("global_load_dwordx4 %0, %1, off" : "=v"(dst) : "v"(p))
// agent-coherent (sc1) ops: L3 is the coherence point across XCDs
#define PLD(dst, p) asm volatile("global_load_dwordx4 %0, %1, off sc1" : "=v"(dst) : "v"(p) : "memory")
#define PST2(p, v2) asm volatile("global_store_dwordx2 %0, %1, off sc1" :: "v"(p), "v"(v2) : "memory")
#define MFMA(a, b, c) __builtin_amdgcn_mfma_f32_16x16x32_bf16(a, b, c, 0, 0, 0)

// ------- prep: Wih->bf16; V0 slots {pay,tag=0} in buf0; buf1 tags=~0 -------
__global__ void prep_kernel(const float* __restrict__ x, const float* __restrict__ Q0,
                            const float* __restrict__ Wih, const float* __restrict__ uVr,
                            const float* __restrict__ uV2,
                            u16* __restrict__ Wih_bf, u32* __restrict__ Vpt) {
  const int NW = 2048 * 1024;
  int stride = gridDim.x * blockDim.x;
  int gid = blockIdx.x * blockDim.x + threadIdx.x;
  for (int i = gid; i < NW; i += stride) Wih_bf[i] = f2bf(Wih[i]);
  for (int p = gid; p < 32768; p += stride) {          // 64 rows x 512 k-pairs
    int s = p * 2;                                     // u32 slot base = row*1024 + 2*kp
    int h0 = s & 1023;
    float g0 = sigmoidf_(uV2[h0]) * tanhf(uVr[h0]);
    float g1 = sigmoidf_(uV2[h0 + 1]) * tanhf(uVr[h0 + 1]);
    u32 pay = (u32)f2bf(x[s] + g0 * Q0[s]) |
              ((u32)f2bf(x[s + 1] + g1 * Q0[s + 1]) << 16);
    Vpt[s] = pay;            Vpt[s + 1] = 0u;          // V_0, tag 0
    Vpt[VBUF + s] = 0u;      Vpt[VBUF + s + 1] = 0xFFFFFFFFu;  // buf1 invalid
  }
}

// ---------------- A_all = x @ WA^T  (M=32768,N=1024,K=1024), bf16 out ------
__global__ __launch_bounds__(256) void agemm_kernel(const float* __restrict__ X,
                                                    const float* __restrict__ W,
                                                    u16* __restrict__ C) {
  __shared__ u16 As[128 * 64];
  __shared__ u16 Bs[128 * 64];
  int tid = threadIdx.x;
  int l = tid & 63, w = tid >> 6;
  int n = l & 15, rowg = l >> 4;
  int wr = w >> 1, wc = w & 1;
  int bm = blockIdx.x >> 3, bn = blockIdx.x & 7;
  long m0 = (long)bm * 128;
  int n0 = bn * 128;
  int srow = tid >> 4;
  int sk4 = (tid & 15) * 4;

  f32x4 acc[4][4];
#pragma unroll
  for (int r = 0; r < 4; ++r)
#pragma unroll
    for (int c = 0; c < 4; ++c) acc[r][c] = (f32x4){0.f, 0.f, 0.f, 0.f};

  for (int kt = 0; kt < 16; ++kt) {
    __syncthreads();
#pragma unroll
    for (int i = 0; i < 8; ++i) {
      int row = srow + i * 16;
      float4 va = *(const float4*)(X + (m0 + row) * 1024 + kt * 64 + sk4);
      u32 lo = (u32)f2bf(va.x) | ((u32)f2bf(va.y) << 16);
      u32 hi = (u32)f2bf(va.z) | ((u32)f2bf(va.w) << 16);
      *(uint2*)(As + row * 64 + sk4) = make_uint2(lo, hi);
      float4 vb = *(const float4*)(W + (long)(n0 + row) * 1024 + kt * 64 + sk4);
      u32 lo2 = (u32)f2bf(vb.x) | ((u32)f2bf(vb.y) << 16);
      u32 hi2 = (u32)f2bf(vb.z) | ((u32)f2bf(vb.w) << 16);
      *(uint2*)(Bs + row * 64 + sk4) = make_uint2(lo2, hi2);
    }
    __syncthreads();
#pragma unroll
    for (int ks = 0; ks < 2; ++ks) {
      short8 af[4], bfr[4];
#pragma unroll
      for (int r = 0; r < 4; ++r)
        af[r] = *(const short8*)(As + (wr * 64 + r * 16 + n) * 64 + ks * 32 + rowg * 8);
#pragma unroll
      for (int c = 0; c < 4; ++c)
        bfr[c] = *(const short8*)(Bs + (wc * 64 + c * 16 + n) * 64 + ks * 32 + rowg * 8);
#pragma unroll
      for (int r = 0; r < 4; ++r)
#pragma unroll
        for (int c = 0; c < 4; ++c)
          acc[r][c] = __builtin_amdgcn_mfma_f32_16x16x32_bf16(af[r], bfr[c], acc[r][c], 0, 0, 0);
    }
  }
#pragma unroll
  for (int r = 0; r < 4; ++r)
#pragma unroll
    for (int c = 0; c < 4; ++c)
#pragma unroll
      for (int q = 0; q < 4; ++q) {
        long row = m0 + wr * 64 + r * 16 + rowg * 4 + q;
        int col = n0 + wc * 64 + c * 16 + n;
        C[row * 1024 + col] = f2bf(acc[r][c][q]);
      }
}

// ---------------- persistent scan (r7 + selective predicated retry) --------
// 64 blocks = 4 bg (16 rows) x 16 hg (64 h), 512 thr = 8 waves, K-split 128/wave.
// V slots {pay(2bf16), tag=t} via one dwordx2 sc1: no drain, no flags; each
// 8B store is atomic and self-validating. Consumer: ONE full sweep, then
// re-load ONLY stale 16B slots (exec-masked) -> no L3 retry storm.
__global__ __launch_bounds__(512, 2)
void scan_kernel(const u16* __restrict__ Wih_bf, const u16* __restrict__ A_bf,
                 const float* __restrict__ x, const float* __restrict__ S0,
                 const float* __restrict__ PFB, const float* __restrict__ HWb,
                 const float* __restrict__ uVr, const float* __restrict__ uV2,
                 u32* __restrict__ Vpt, float* __restrict__ out) {
  __shared__ f32x4 red[8][8][64];              // [j-tile][wave][lane]
  const int tid = threadIdx.x, bk = blockIdx.x;
  const int bg = bk >> 4, hg = bk & 15;
  const int l = tid & 63, w = tid >> 6;
  const int n = l & 15, rowg = l >> 4, hl = n & 7;
  const bool isF = (n < 8);
  const int h = hg * 64 + w * 8 + hl;          // wave w's output h (post-reduce)

  // weights: 8 j-tiles x 4 k-slices = 32 short8 = 128 regs, asm-pinned
  short8 bw[8][4];
  {
    const int fOff = isF ? 0 : HDim;
#pragma unroll
    for (int jt = 0; jt < 8; ++jt) {
      const u16* wp = Wih_bf + (long)(fOff + hg * 64 + jt * 8 + hl) * 1024 + w * 128 + rowg * 8;
      WLD(bw[jt][0], wp);      WLD(bw[jt][1], wp + 32);
      WLD(bw[jt][2], wp + 64); WLD(bw[jt][3], wp + 96);
    }
  }
  WAITVM(0); SBAR();

  const float pfb = PFB[h], hwb = HWb[h];
  const float gh = sigmoidf_(uV2[h]) * tanhf(uVr[h]);

  const int row0 = bg * 16 + rowg * 4;
  int rowoff[4];
  float S[4];
#pragma unroll
  for (int r = 0; r < 4; ++r) { rowoff[r] = (row0 + r) * 1024 + h; S[r] = S0[rowoff[r]]; }

  // sweep/A-frag base: row = bg*16 + n, k = w*128 + s*32 + rowg*8 (+e)
  const u32* pbase = Vpt + (bg * 16 + n) * 1024 + w * 128 + rowg * 8;

  float xq[4], xn[4], av[4], Qs[4];
#pragma unroll
  for (int r = 0; r < 4; ++r) {
    xq[r] = x[rowoff[r]];
    xn[r] = x[NBH + rowoff[r]];
    av[r] = bf2f(A_bf[rowoff[r]]);
  }

#pragma unroll 1
  for (int t = 0; t < TT; ++t) {
    const u32 tv = (u32)t;
    const int half = (t & 1);

    // ---- poll = data read. First full sweep, then reload ONLY stale slots.
    const u32* pb = pbase + half * VBUF;
    u32x4 q0a, q0b, q1a, q1b, q2a, q2b, q3a, q3b;
    PLD(q0a, pb);      PLD(q0b, pb + 4);
    PLD(q1a, pb + 32); PLD(q1b, pb + 36);
    PLD(q2a, pb + 64); PLD(q2b, pb + 68);
    PLD(q3a, pb + 96); PLD(q3b, pb + 100);
    WAITVM(0); SBAR();
    {
      bool s0a = (q0a[1] != tv) | (q0a[3] != tv);
      bool s0b = (q0b[1] != tv) | (q0b[3] != tv);
      bool s1a = (q1a[1] != tv) | (q1a[3] != tv);
      bool s1b = (q1b[1] != tv) | (q1b[3] != tv);
      bool s2a = (q2a[1] != tv) | (q2a[3] != tv);
      bool s2b = (q2b[1] != tv) | (q2b[3] != tv);
      bool s3a = (q3a[1] != tv) | (q3a[3] != tv);
      bool s3b = (q3b[1] != tv) | (q3b[3] != tv);
      while (__any(s0a | s0b | s1a | s1b | s2a | s2b | s3a | s3b)) {
        if (s0a) PLD(q0a, pb);
        if (s0b) PLD(q0b, pb + 4);
        if (s1a) PLD(q1a, pb + 32);
        if (s1b) PLD(q1b, pb + 36);
        if (s2a) PLD(q2a, pb + 64);
        if (s2b) PLD(q2b, pb + 68);
        if (s3a) PLD(q3a, pb + 96);
        if (s3b) PLD(q3b, pb + 100);
        WAITVM(0); SBAR();
        s0a = (q0a[1] != tv) | (q0a[3] != tv);
        s0b = (q0b[1] != tv) | (q0b[3] != tv);
        s1a = (q1a[1] != tv) | (q1a[3] != tv);
        s1b = (q1b[1] != tv) | (q1b[3] != tv);
        s2a = (q2a[1] != tv) | (q2a[3] != tv);
        s2b = (q2b[1] != tv) | (q2b[3] != tv);
        s3a = (q3a[1] != tv) | (q3a[3] != tv);
        s3b = (q3b[1] != tv) | (q3b[3] != tv);
      }
    }

    // ---- deferred Y stores from previous step (ack drains under compute)
    if (t > 0) {
      const long pvbase = (long)(t - 1) * NBH;
#pragma unroll
      for (int r = 0; r < 4; ++r)
        if (isF) out[pvbase + rowoff[r]] = Qs[r];
    }

    // ---- extract payloads -> A fragments; MFMA (data already in regs)
    u32x4 p0 = {q0a[0], q0a[2], q0b[0], q0b[2]};
    u32x4 p1 = {q1a[0], q1a[2], q1b[0], q1b[2]};
    u32x4 p2 = {q2a[0], q2a[2], q2b[0], q2b[2]};
    u32x4 p3 = {q3a[0], q3a[2], q3b[0], q3b[2]};
    short8 va0 = __builtin_bit_cast(short8, p0);
    short8 va1 = __builtin_bit_cast(short8, p1);
    short8 va2 = __builtin_bit_cast(short8, p2);
    short8 va3 = __builtin_bit_cast(short8, p3);

    f32x4 pa[8];
#pragma unroll
    for (int jt = 0; jt < 8; ++jt) pa[jt] = (f32x4){0.f, 0.f, 0.f, 0.f};
#pragma unroll
    for (int jt = 0; jt < 8; ++jt) pa[jt] = MFMA(va0, bw[jt][0], pa[jt]);
#pragma unroll
    for (int jt = 0; jt < 8; ++jt) pa[jt] = MFMA(va1, bw[jt][1], pa[jt]);
#pragma unroll
    for (int jt = 0; jt < 8; ++jt) pa[jt] = MFMA(va2, bw[jt][2], pa[jt]);
#pragma unroll
    for (int jt = 0; jt < 8; ++jt) pa[jt] = MFMA(va3, bw[jt][3], pa[jt]);

    // ---- cross-wave K-reduction
#pragma unroll
    for (int jt = 0; jt < 8; ++jt) red[jt][w][l] = pa[jt];
    __syncthreads();
    f32x4 fr = red[w][0][l] + red[w][1][l] + red[w][2][l] + red[w][3][l]
             + red[w][4][l] + red[w][5][l] + red[w][6][l] + red[w][7][l];
    __syncthreads();                            // protect red reuse next step

    // ---- gates, state update, tagged V stores (fire-and-forget)
    u32* vnext = Vpt + ((t + 1) & 1) * VBUF;
    const long tbase = (long)t * NBH;
#pragma unroll
    for (int r = 0; r < 4; ++r) {
      float mine = fr[r];
      float other = __shfl_xor(mine, 8, 64);
      float Fi = isF ? mine : other;
      float Ri = isF ? other : mine;
      float F = sigmoidf_(Fi + pfb);
      float Rg = sigmoidf_(Ri + hwb);
      S[r] = F * S[r] + (1.0f - F) * av[r];
      float Q = Rg * S[r] + (1.0f - Rg) * xq[r];
      Qs[r] = Q;
      if (t < TT - 1) {
        u32 word = (u32)f2bf(xn[r] + gh * Q);
        u32 othw = (u32)__shfl_xor((int)word, 1, 64);
        if (isF && (hl & 1) == 0) {
          u32x2 pv = {word | (othw << 16), (u32)(t + 1)};
          PST2(vnext + rowoff[r], pv);          // {pay, tag} in one 8B store
        }
      }
    }

    if (t == TT - 1) {
#pragma unroll
      for (int r = 0; r < 4; ++r)
        if (isF) {
          out[tbase + rowoff[r]] = Qs[r];
          out[(long)TT * NBH + rowoff[r]] = Qs[r];            // Qf
          out[(long)TT * NBH + NBH + rowoff[r]] = S[r];       // Sf
        }
      break;
    }

    // ---- prefetch next step's scalars (in flight across the next poll)
    const long nb = tbase + NBH;
    const int tn = (t + 2 < TT) ? (t + 2) : (TT - 1);
    const long nb2 = (long)tn * NBH;
#pragma unroll
    for (int r = 0; r < 4; ++r) {
      xq[r] = x[nb + rowoff[r]];
      av[r] = bf2f(A_bf[nb + rowoff[r]]);
      xn[r] = x[nb2 + rowoff[r]];
    }
  }
}

extern "C" void kernel_launch(void* const* d_in, const int* in_sizes, int n_in,
                              void* d_out, int out_size, void* d_ws, size_t ws_size,
                              hipStream_t stream) {
  const float* x   = (const float*)d_in[0];
  const float* Q0  = (const float*)d_in[1];
  const float* S0  = (const float*)d_in[2];
  const float* Wih = (const float*)d_in[3];
  const float* WA  = (const float*)d_in[4];
  const float* uVr = (const float*)d_in[5];
  const float* uV2 = (const float*)d_in[6];
  const float* PFB = (const float*)d_in[7];
  const float* HWb = (const float*)d_in[8];
  float* out = (float*)d_out;

  char* ws = (char*)d_ws;
  u16* A_bf   = (u16*)(ws);                 // 67,108,864 B : A_all bf16 [T*B][HD]
  u16* Wih_bf = (u16*)(ws + 67108864);      //  4,194,304 B
  u32* Vpt    = (u32*)(ws + 71303168);      //    524,288 B : ping-pong {pay,tag}
  (void)in_sizes; (void)n_in; (void)out_size; (void)ws_size;

  prep_kernel<<<2048, 256, 0, stream>>>(x, Q0, Wih, uVr, uV2, Wih_bf, Vpt);
  agemm_kernel<<<2048, 256, 0, stream>>>(x, WA, A_bf);
  scan_kernel<<<NBLK, 512, 0, stream>>>(Wih_bf, A_bf, x, S0, PFB, HWb, uVr, uV2, Vpt, out);
}

// Round 14
// 1275.938 us; speedup vs baseline: 2.1836x; 1.9149x over previous
//
#include <hip/hip_runtime.h>

typedef __attribute__((ext_vector_type(8))) short short8;   // 8 bf16 in 4 VGPRs
typedef __attribute__((ext_vector_type(4))) float f32x4;
typedef unsigned short u16;
typedef unsigned int u32;

static constexpr int TT = 512;
static constexpr int BB = 64;
static constexpr int HDim = 1024;
static constexpr int NBH = BB * HDim;          // 65536
static constexpr int TC = 64;                  // chunk length (8 chunks)
static constexpr int CROWS = TC * BB;          // 4096 GEMM rows per chunk
static constexpr int LDC = 3072;               // FR leading dim (Fi|Ri|A)

__device__ __forceinline__ u16 f2bf(float f) {             // RNE f32->bf16
  u32 u = __float_as_uint(f);
  u32 r = u + 0x7FFFu + ((u >> 16) & 1u);
  return (u16)(r >> 16);
}
__device__ __forceinline__ float bf2f(u16 u) {
  return __uint_as_float(((u32)u) << 16);
}
__device__ __forceinline__ float sigmoidf_(float v) {
  return 1.0f / (1.0f + __expf(-v));
}

// ---- prep: Wcat=[Wih;WA]->bf16; QP row0 = g*Q0; Sb = S0 (re-init per call) --
__global__ void prep_kernel(const float* __restrict__ Q0, const float* __restrict__ S0,
                            const float* __restrict__ Wih, const float* __restrict__ WA,
                            const float* __restrict__ uVr, const float* __restrict__ uV2,
                            u16* __restrict__ Wcat, u16* __restrict__ QP,
                            float* __restrict__ Sb) {
  const int NWC = 3072 * 1024;
  int stride = gridDim.x * blockDim.x;
  int gid = blockIdx.x * blockDim.x + threadIdx.x;
  for (int i = gid; i < NWC; i += stride)
    Wcat[i] = f2bf(i < 2048 * 1024 ? Wih[i] : WA[i - 2048 * 1024]);
  for (int j = gid; j < NBH; j += stride) {
    int h = j & (HDim - 1);
    float g = sigmoidf_(uV2[h]) * tanhf(uVr[h]);
    QP[j] = f2bf(g * Q0[j]);                   // V_0 correction term (exact)
    Sb[j] = S0[j];                             // boundary state
  }
}

// ---- chunk GEMM: FR[0..4096)[0..N) = (X (+QP)) @ Wcat^T, fp32 out ---------
// ADD_QP=false: N=3072 (Fi|Ri|A), x-only.  ADD_QP=true: N=2048, V=x+QP.
template<bool ADD_QP>
__global__ __launch_bounds__(256) void gemm_kernel(const float* __restrict__ X,
                                                   const u16* __restrict__ QP,
                                                   const u16* __restrict__ W,
                                                   float* __restrict__ FR, int nbc) {
  __shared__ u16 As[128 * 64];
  __shared__ u16 Bs[128 * 64];
  int tid = threadIdx.x;
  int l = tid & 63, w = tid >> 6;
  int n = l & 15, rowg = l >> 4;
  int wr = w >> 1, wc = w & 1;
  int bm = blockIdx.x / nbc, bn = blockIdx.x % nbc;
  int m0 = bm * 128;
  int n0 = bn * 128;
  int srow = tid >> 4;        // 0..15
  int sk4 = (tid & 15) * 4;   // 0..60

  f32x4 acc[4][4];
#pragma unroll
  for (int r = 0; r < 4; ++r)
#pragma unroll
    for (int c = 0; c < 4; ++c) acc[r][c] = (f32x4){0.f, 0.f, 0.f, 0.f};

  for (int kt = 0; kt < 16; ++kt) {
    __syncthreads();
#pragma unroll
    for (int i = 0; i < 8; ++i) {
      int row = srow + i * 16;
      float4 va = *(const float4*)(X + (m0 + row) * 1024 + kt * 64 + sk4);
      if constexpr (ADD_QP) {
        uint2 qp = *(const uint2*)(QP + (m0 + row) * 1024 + kt * 64 + sk4);
        va.x += bf2f((u16)(qp.x & 0xFFFFu));
        va.y += bf2f((u16)(qp.x >> 16));
        va.z += bf2f((u16)(qp.y & 0xFFFFu));
        va.w += bf2f((u16)(qp.y >> 16));
      }
      u32 lo = (u32)f2bf(va.x) | ((u32)f2bf(va.y) << 16);
      u32 hi = (u32)f2bf(va.z) | ((u32)f2bf(va.w) << 16);
      *(uint2*)(As + row * 64 + sk4) = make_uint2(lo, hi);
      float4 vb = *(const float4*)(0 ? (const float*)0 : (const float*)0);
      (void)vb;
      // B tile: Wcat rows n0+row (already bf16)
      uint2 wb = *(const uint2*)(W + (n0 + row) * 1024 + kt * 64 + sk4);
      *(uint2*)(Bs + row * 64 + sk4) = make_uint2(wb.x, wb.y);
    }
    __syncthreads();
#pragma unroll
    for (int ks = 0; ks < 2; ++ks) {
      short8 af[4], bfr[4];
#pragma unroll
      for (int r = 0; r < 4; ++r)
        af[r] = *(const short8*)(As + (wr * 64 + r * 16 + n) * 64 + ks * 32 + rowg * 8);
#pragma unroll
      for (int c = 0; c < 4; ++c)
        bfr[c] = *(const short8*)(Bs + (wc * 64 + c * 16 + n) * 64 + ks * 32 + rowg * 8);
#pragma unroll
      for (int r = 0; r < 4; ++r)
#pragma unroll
        for (int c = 0; c < 4; ++c)
          acc[r][c] = __builtin_amdgcn_mfma_f32_16x16x32_bf16(af[r], bfr[c], acc[r][c], 0, 0, 0);
    }
  }
#pragma unroll
  for (int r = 0; r < 4; ++r)
#pragma unroll
    for (int c = 0; c < 4; ++c)
#pragma unroll
      for (int q = 0; q < 4; ++q) {
        int row = m0 + wr * 64 + r * 16 + rowg * 4 + q;
        int col = n0 + wc * 64 + c * 16 + n;
        FR[row * LDC + col] = acc[r][c][q];
      }
}

// ---- chunk scan: per-(b,h) sequential over TC steps (no inter-block deps) --
// FINAL=false (it1): write QP rows 1..63 = g*Q^(1).
// FINAL=true  (it2): write Y; commit QP row0 = g*Q_last and Sb; Qf/Sf at end.
template<bool FINAL>
__global__ __launch_bounds__(256) void scan_pass(const float* __restrict__ FR,
                                                 const float* __restrict__ X,
                                                 const float* __restrict__ PFB,
                                                 const float* __restrict__ HWb,
                                                 const float* __restrict__ uVr,
                                                 const float* __restrict__ uV2,
                                                 u16* __restrict__ QP,
                                                 float* __restrict__ Sb,
                                                 float* __restrict__ out, int t0) {
  const int gid = blockIdx.x * blockDim.x + threadIdx.x;   // 65536 threads
  const int b = gid >> 10, h = gid & 1023;
  const float pfb = PFB[h], hwb = HWb[h];
  const float g = sigmoidf_(uV2[h]) * tanhf(uVr[h]);
  float S = Sb[gid];
  float Q = 0.f;

#pragma unroll 4
  for (int r = 0; r < TC; ++r) {
    const int row = r * BB + b;
    float Fi = FR[row * LDC + h];
    float Ri = FR[row * LDC + 1024 + h];
    float Av = FR[row * LDC + 2048 + h];
    float xv = X[row * 1024 + h];
    float F = sigmoidf_(Fi + pfb);
    float R = sigmoidf_(Ri + hwb);
    S = F * S + (1.0f - F) * Av;
    Q = R * S + (1.0f - R) * xv;
    if constexpr (!FINAL) {
      if (r < TC - 1) QP[(row + BB) * 1024 + h] = f2bf(g * Q);
    } else {
      out[(long)(t0 + r) * NBH + b * 1024 + h] = Q;
    }
  }
  if constexpr (FINAL) {
    QP[b * 1024 + h] = f2bf(g * Q);            // boundary for next chunk
    Sb[gid] = S;
    if (t0 == TT - TC) {
      out[(long)TT * NBH + gid] = Q;           // Qf
      out[(long)TT * NBH + NBH + gid] = S;     // Sf
    }
  }
}

extern "C" void kernel_launch(void* const* d_in, const int* in_sizes, int n_in,
                              void* d_out, int out_size, void* d_ws, size_t ws_size,
                              hipStream_t stream) {
  const float* x   = (const float*)d_in[0];
  const float* Q0  = (const float*)d_in[1];
  const float* S0  = (const float*)d_in[2];
  const float* Wih = (const float*)d_in[3];
  const float* WA  = (const float*)d_in[4];
  const float* uVr = (const float*)d_in[5];
  const float* uV2 = (const float*)d_in[6];
  const float* PFB = (const float*)d_in[7];
  const float* HWb = (const float*)d_in[8];
  float* out = (float*)d_out;

  char* ws = (char*)d_ws;
  float* FR   = (float*)(ws);               // 50,331,648 B : chunk FR fp32 [4096][3072]
  u16*   QP   = (u16*)(ws + 50331648);      //  8,388,608 B : chunk QP bf16 [4096][1024]
  u16*   Wcat = (u16*)(ws + 58720256);      //  6,291,456 B : [Wih;WA] bf16 [3072][1024]
  float* Sb   = (float*)(ws + 65011712);    //    262,144 B : boundary S [65536]
  (void)in_sizes; (void)n_in; (void)out_size; (void)ws_size;

  prep_kernel<<<2048, 256, 0, stream>>>(Q0, S0, Wih, WA, uVr, uV2, Wcat, QP, Sb);

  for (int c = 0; c < TT / TC; ++c) {
    const float* xc = x + (long)c * TC * NBH;
    const int t0 = c * TC;
    // it1: FR = x @ [Wih;WA]^T  (Fi|Ri|A), no boundary term
    gemm_kernel<false><<<32 * 24, 256, 0, stream>>>(xc, QP, Wcat, FR, 24);
    // scan1 (approx) -> QP rows 1..63
    scan_pass<false><<<256, 256, 0, stream>>>(FR, xc, PFB, HWb, uVr, uV2, QP, Sb, out, t0);
    // it2: FR[:, 0..2048) = (x + QP) @ Wih^T  (exact boundary via QP row0)
    gemm_kernel<true><<<32 * 16, 256, 0, stream>>>(xc, QP, Wcat, FR, 16);
    // scan2 (final) -> Y, boundary commit, Qf/Sf on last chunk
    scan_pass<true><<<256, 256, 0, stream>>>(FR, xc, PFB, HWb, uVr, uV2, QP, Sb, out, t0);
  }
}